// Round 3
// baseline (616.068 us; speedup 1.0000x reference)
//
#include <hip/hip_runtime.h>
#include <cstdint>

// DimeNet interaction block, MI355X/gfx950.
// DTYPES (round-2 root cause): reference declares float32 everywhere ->
//   d_in float tensors are const float*, indices const int*, d_out float*.
//   (Rounds 1-2 read them as bf16: even 16-bit words of f32 data decode to
//   Inf/NaN ~0.4% of the time -> NaN output. One cause, both rounds.)
// Internals: f32 -> f16 MFMA operands, fp32 accumulate, fp32 epilogues.
// Memory plan:
//   agg  = f32 [E][H], aliased 1:1 onto d_out (same-row ownership in post ->
//          read-then-overwrite per block is race-free; edge fully initializes
//          rows < E with x_ji before bilinear atomics touch them).
//   x_kj = f16 [E][H] in d_ws (25.6 MB, sole workspace use).
// Pipeline: edge -> bilinear (gather + inline sbf + per-j GEMM + f32 atomic
//           scatter) -> post (7 fused 128x128 GEMM stages -> f32 out).

#define H 128
#define NB 8
#define NR 6
#define SBC 42
#define LDA 136   // f16 lane pad: 128 + 8
#define LDF 132   // f32 lane pad: 128 + 4

using f16x8 = __attribute__((ext_vector_type(8))) _Float16;
using f32x4 = __attribute__((ext_vector_type(4))) float;

__device__ __forceinline__ float silu_f(float v){
  return v / (1.f + __expf(-v));
}
__device__ __forceinline__ f16x8 pack8(float4 a, float4 b){
  f16x8 h;
  h[0]=(_Float16)a.x; h[1]=(_Float16)a.y; h[2]=(_Float16)a.z; h[3]=(_Float16)a.w;
  h[4]=(_Float16)b.x; h[5]=(_Float16)b.y; h[6]=(_Float16)b.z; h[7]=(_Float16)b.w;
  return h;
}

// stage 128x128 f32 weight [k][n] -> LDS [n][k] f16 (transpose + convert).
// Thread t: rows k0,k0+1, cols c0..c0+31; paired-k u32 LDS writes (4B aligned,
// lane-linear k0 -> 2-way bank aliasing only, free).
__device__ __forceinline__ void stage_wT(const float* __restrict__ w,
                                         _Float16* __restrict__ sB, int tid){
  int k0 = (tid & 63) * 2;
  int c0 = (tid >> 6) * 32;
  const float4* p0 = reinterpret_cast<const float4*>(w + (size_t)k0*H + c0);
  const float4* p1 = reinterpret_cast<const float4*>(w + (size_t)(k0+1)*H + c0);
  #pragma unroll
  for (int i=0;i<8;i++){
    float4 u0 = p0[i], u1 = p1[i];
    float a0[4] = {u0.x,u0.y,u0.z,u0.w};
    float a1[4] = {u1.x,u1.y,u1.z,u1.w};
    #pragma unroll
    for (int j=0;j<4;j++){
      unsigned int bits =
          (unsigned int)__builtin_bit_cast(unsigned short, (_Float16)a0[j])
        | ((unsigned int)__builtin_bit_cast(unsigned short, (_Float16)a1[j]) << 16);
      *reinterpret_cast<unsigned int*>(&sB[(c0+i*4+j)*LDA + k0]) = bits;
    }
  }
}

// ---------------- edge: x_kj -> ws (f16), agg(init)=x_ji -> d_out (f32) ----------------
__global__ __launch_bounds__(256,2) void edge_kernel(
    const float* __restrict__ x,
    const float* __restrict__ radial,
    const float* __restrict__ w_rbf,
    const float* __restrict__ w_from,
    const float* __restrict__ b_from,
    const float* __restrict__ w_to,
    const float* __restrict__ b_to,
    _Float16* __restrict__ x_kj, float* __restrict__ agg, int E)
{
  __shared__ alignas(16) _Float16 sA[64*LDA];
  __shared__ alignas(16) _Float16 sB[128*LDA];
  __shared__ alignas(16) _Float16 sO[64*LDA];
  __shared__ float sRad[64*8];
  __shared__ float sWr[128*8];
  __shared__ float sBias[128];
  int tid = threadIdx.x;
  int e0 = blockIdx.x*64;
  int wave = tid>>6, lane = tid&63, l15 = lane&15, q = lane>>4;

  { // stage x tile (f32 -> f16), zero OOB rows
    int row = tid>>2, cs = (tid&3)*32;
    bool ok = (e0+row) < E;
    const float4* src = reinterpret_cast<const float4*>(x + (size_t)(e0+row)*H + cs);
    #pragma unroll
    for (int i=0;i<4;i++){
      float4 u0{0,0,0,0}, u1{0,0,0,0};
      if (ok){ u0 = src[2*i]; u1 = src[2*i+1]; }
      *reinterpret_cast<f16x8*>(&sA[row*LDA + cs + i*8]) = pack8(u0,u1);
    }
  }
  for (int i=tid; i<64*NR; i+=256){
    int r=i/NR, c=i%NR;
    sRad[r*8+c] = (e0+r < E) ? radial[(size_t)(e0+r)*NR + c] : 0.f;
  }
  for (int i=tid; i<NR*H; i+=256){
    int c=i>>7, n=i&127;
    sWr[n*8+c] = w_rbf[i];
  }
  if (tid < H) sBias[tid] = b_from[tid];
  stage_wT(w_from, sB, tid);
  __syncthreads();

  f32x4 acc[8];
  auto gemm = [&](){
    #pragma unroll
    for (int nt=0;nt<8;nt++) acc[nt] = f32x4{0.f,0.f,0.f,0.f};
    int ar = (wave*16 + l15)*LDA;
    #pragma unroll
    for (int kk=0;kk<4;kk++){
      f16x8 a = *reinterpret_cast<const f16x8*>(&sA[ar + kk*32 + q*8]);
      #pragma unroll
      for (int nt=0;nt<8;nt++){
        f16x8 b = *reinterpret_cast<const f16x8*>(&sB[(nt*16+l15)*LDA + kk*32 + q*8]);
        acc[nt] = __builtin_amdgcn_mfma_f32_16x16x32_f16(a, b, acc[nt], 0,0,0);
      }
    }
  };

  gemm();  // x @ w_from
  #pragma unroll
  for (int nt=0;nt<8;nt++)
    #pragma unroll
    for (int r=0;r<4;r++){
      int rl = wave*16 + q*4 + r, col = nt*16 + l15;
      float v = silu_f(acc[nt][r] + sBias[col]);
      float rb = 0.f;
      #pragma unroll
      for (int c=0;c<NR;c++) rb += sRad[rl*8+c]*sWr[col*8+c];
      sO[rl*LDA+col] = (_Float16)(v*rb);
    }
  __syncthreads();
  { // coalesced f16 store x_kj -> ws
    int row=tid>>2, cs=(tid&3)*32;
    if (e0+row < E)
      #pragma unroll
      for (int i=0;i<4;i++)
        *reinterpret_cast<f16x8*>(x_kj + (size_t)(e0+row)*H + cs + i*8) =
          *reinterpret_cast<const f16x8*>(&sO[row*LDA + cs + i*8]);
  }
  if (tid < H) sBias[tid] = b_to[tid];
  stage_wT(w_to, sB, tid);
  __syncthreads();
  gemm();  // x @ w_to
  #pragma unroll
  for (int nt=0;nt<8;nt++)
    #pragma unroll
    for (int r=0;r<4;r++){
      int rl = wave*16 + q*4 + r, col = nt*16 + l15;
      sO[rl*LDA+col] = (_Float16)silu_f(acc[nt][r] + sBias[col]);
    }
  __syncthreads();
  { // agg init = x_ji, f32 store into d_out
    int row=tid>>2, cs=(tid&3)*32;
    if (e0+row < E)
      #pragma unroll
      for (int i=0;i<4;i++){
        f16x8 v = *reinterpret_cast<const f16x8*>(&sO[row*LDA + cs + i*8]);
        float4 lo{(float)v[0],(float)v[1],(float)v[2],(float)v[3]};
        float4 hi{(float)v[4],(float)v[5],(float)v[6],(float)v[7]};
        float4* dp = reinterpret_cast<float4*>(agg + (size_t)(e0+row)*H + cs + i*8);
        dp[0] = lo; dp[1] = hi;
      }
  }
}

// ---------------- bilinear + f32 atomic scatter ----------------
__global__ __launch_bounds__(256,2) void bilinear_kernel(
    const _Float16* __restrict__ x_kj,
    const float* __restrict__ sph,
    const float* __restrict__ w_sbf,
    const float* __restrict__ Wb,
    const int* __restrict__ e_from, const int* __restrict__ e_to,
    float* __restrict__ agg)
{
  __shared__ alignas(16) _Float16 gth[128*LDA];
  __shared__ alignas(16) _Float16 wch[128*LDA];   // also f32 scratch for sph rows
  __shared__ float ssb[128*NB];
  __shared__ float sw[SBC*NB];
  __shared__ int sdst[128];
  int tid = threadIdx.x;
  long long t0 = (long long)blockIdx.x * 128;
  int row = tid>>1, half = tid&1;

  { // gather x_kj rows (f16, from ws)
    int src = e_from[t0 + row];
    const f16x8* sp = reinterpret_cast<const f16x8*>(x_kj + (size_t)src*H + half*64);
    f16x8* dp = reinterpret_cast<f16x8*>(&gth[row*LDA + half*64]);
    #pragma unroll
    for (int i=0;i<8;i++) dp[i] = sp[i];
  }
  { // stage 128 spherical rows (f32) into wch scratch, coalesced float4
    float4* scr = reinterpret_cast<float4*>(wch);
    const float4* g = reinterpret_cast<const float4*>(sph + t0*SBC);
    for (int i=tid; i<128*SBC/4; i+=256) scr[i] = g[i];
  }
  for (int i=tid; i<SBC*NB; i+=256) sw[i] = w_sbf[i];
  if (tid < 128) sdst[tid] = e_to[t0 + tid];
  __syncthreads();
  { // inline sbf: row=tid>>1, cols half*4..half*4+3
    const float* srow = reinterpret_cast<const float*>(wch) + row*SBC;
    float a4[4] = {0.f,0.f,0.f,0.f};
    for (int c=0;c<SBC;c++){
      float v = srow[c];
      #pragma unroll
      for (int cc=0;cc<4;cc++) a4[cc] += v * sw[c*NB + half*4 + cc];
    }
    #pragma unroll
    for (int cc=0;cc<4;cc++) ssb[row*NB + half*4 + cc] = a4[cc];
  }

  int wave = tid>>6, lane = tid&63, l15 = lane&15, q = lane>>4;
  int m0 = wave*32;
  f32x4 acc[2][8];
  #pragma unroll
  for (int mt=0;mt<2;mt++)
    #pragma unroll
    for (int nt=0;nt<8;nt++) acc[mt][nt] = f32x4{0.f,0.f,0.f,0.f};

  for (int jj=0;jj<NB;jj++){
    __syncthreads();   // sbf-scratch / prev-W reads of wch complete
    { // stage W[:, jj, :] f32 -> f16 as Bt[n=i][k=l]
      const float4* wp = reinterpret_cast<const float4*>(Wb + (size_t)row*1024 + jj*128 + half*64);
      f16x8* dp = reinterpret_cast<f16x8*>(&wch[row*LDA + half*64]);
      #pragma unroll
      for (int u=0;u<8;u++) dp[u] = pack8(wp[2*u], wp[2*u+1]);
    }
    __syncthreads();
    _Float16 s0 = (_Float16)ssb[(m0+l15)*NB + jj];
    _Float16 s1 = (_Float16)ssb[(m0+16+l15)*NB + jj];
    #pragma unroll
    for (int kk=0;kk<4;kk++){
      f16x8 a0 = *reinterpret_cast<const f16x8*>(&gth[(m0+l15)*LDA + kk*32 + q*8]);
      f16x8 a1 = *reinterpret_cast<const f16x8*>(&gth[(m0+16+l15)*LDA + kk*32 + q*8]);
      a0 *= s0; a1 *= s1;    // A-fragment = sbf[w][jj] * gathered[w][l]
      #pragma unroll
      for (int nt=0;nt<8;nt++){
        f16x8 b = *reinterpret_cast<const f16x8*>(&wch[(nt*16+l15)*LDA + kk*32 + q*8]);
        acc[0][nt] = __builtin_amdgcn_mfma_f32_16x16x32_f16(a0, b, acc[0][nt], 0,0,0);
        acc[1][nt] = __builtin_amdgcn_mfma_f32_16x16x32_f16(a1, b, acc[1][nt], 0,0,0);
      }
    }
  }
  // f32 atomic scatter (native global_atomic_add_f32; avg 2.6 writers/row)
  #pragma unroll
  for (int mt=0;mt<2;mt++)
    #pragma unroll
    for (int nt=0;nt<8;nt++)
      #pragma unroll
      for (int r=0;r<4;r++){
        int rl = m0 + mt*16 + q*4 + r;
        int col = nt*16 + l15;
        unsafeAtomicAdd(&agg[(size_t)sdst[rl]*H + col], acc[mt][nt][r]);
      }
}

// ---------------- post: h=agg, rb residual, lin+skip, ra0, ra1 -> f32 out ----------------
__global__ __launch_bounds__(256,2) void post_kernel(
    const float* __restrict__ x, const float* __restrict__ agg,
    const float* __restrict__ rb_w, const float* __restrict__ rb_b,
    const float* __restrict__ lin_w, const float* __restrict__ lin_b,
    const float* __restrict__ ra_w, const float* __restrict__ ra_b,
    float* __restrict__ out, int E)
{
  __shared__ alignas(16) _Float16 sIn[64*LDA];
  __shared__ alignas(16) _Float16 sW[128*LDA];
  __shared__ float sBias[128];
  int tid = threadIdx.x, e0 = blockIdx.x*64;
  int wave = tid>>6, lane = tid&63, l15 = lane&15, q = lane>>4;

  { // h0 = agg (= x_ji + scattered msg), f32 -> f16
    int row=tid>>2, cs=(tid&3)*32;
    bool ok = (e0+row) < E;
    const float4* ap = reinterpret_cast<const float4*>(agg + (size_t)(e0+row)*H + cs);
    #pragma unroll
    for (int i=0;i<4;i++){
      float4 u0{0,0,0,0}, u1{0,0,0,0};
      if (ok){ u0 = ap[2*i]; u1 = ap[2*i+1]; }
      *reinterpret_cast<f16x8*>(&sIn[row*LDA + cs + i*8]) = pack8(u0,u1);
    }
  }
  __syncthreads();
  float h[8][4];   // C-layout: row=wave*16+q*4+r, col=nt*16+l15
  #pragma unroll
  for (int nt=0;nt<8;nt++)
    #pragma unroll
    for (int r=0;r<4;r++)
      h[nt][r] = (float)sIn[(wave*16+q*4+r)*LDA + nt*16 + l15];

  f32x4 acc[8];
  auto do_gemm = [&](const float* w, const float* bias){
    __syncthreads();   // sIn epilogue writes visible; prior sW reads done
    stage_wT(w, sW, tid);
    if (tid < H) sBias[tid] = bias[tid];
    __syncthreads();
    #pragma unroll
    for (int nt=0;nt<8;nt++) acc[nt] = f32x4{0.f,0.f,0.f,0.f};
    int ar = (wave*16 + l15)*LDA;
    #pragma unroll
    for (int kk=0;kk<4;kk++){
      f16x8 a = *reinterpret_cast<const f16x8*>(&sIn[ar + kk*32 + q*8]);
      #pragma unroll
      for (int nt=0;nt<8;nt++){
        f16x8 b = *reinterpret_cast<const f16x8*>(&sW[(nt*16+l15)*LDA + kk*32 + q*8]);
        acc[nt] = __builtin_amdgcn_mfma_f32_16x16x32_f16(a, b, acc[nt], 0,0,0);
      }
    }
    __syncthreads();   // all sIn/sW reads done -> epilogue may overwrite sIn
  };

  // rb residual: h += silu(silu(h@w1+b1)@w2+b2)
  do_gemm(rb_w, rb_b);
  #pragma unroll
  for (int nt=0;nt<8;nt++)
    #pragma unroll
    for (int r=0;r<4;r++){
      int rl=wave*16+q*4+r, col=nt*16+l15;
      sIn[rl*LDA+col] = (_Float16)silu_f(acc[nt][r] + sBias[col]);
    }
  do_gemm(rb_w + 16384, rb_b + 128);
  #pragma unroll
  for (int nt=0;nt<8;nt++)
    #pragma unroll
    for (int r=0;r<4;r++){
      int rl=wave*16+q*4+r, col=nt*16+l15;
      h[nt][r] += silu_f(acc[nt][r] + sBias[col]);
      sIn[rl*LDA+col] = (_Float16)h[nt][r];
    }
  // lin + skip: h = silu(h@lin+b) + x
  do_gemm(lin_w, lin_b);
  #pragma unroll
  for (int nt=0;nt<8;nt++)
    #pragma unroll
    for (int r=0;r<4;r++){
      int rl=wave*16+q*4+r, col=nt*16+l15;
      bool ok = (e0+rl) < E;
      float xv = ok ? x[(size_t)(e0+rl)*H + col] : 0.f;
      h[nt][r] = silu_f(acc[nt][r] + sBias[col]) + xv;
      sIn[rl*LDA+col] = (_Float16)h[nt][r];
    }
  // ra0 residual
  do_gemm(ra_w, ra_b);
  #pragma unroll
  for (int nt=0;nt<8;nt++)
    #pragma unroll
    for (int r=0;r<4;r++){
      int rl=wave*16+q*4+r, col=nt*16+l15;
      sIn[rl*LDA+col] = (_Float16)silu_f(acc[nt][r] + sBias[col]);
    }
  do_gemm(ra_w + 16384, ra_b + 128);
  #pragma unroll
  for (int nt=0;nt<8;nt++)
    #pragma unroll
    for (int r=0;r<4;r++){
      int rl=wave*16+q*4+r, col=nt*16+l15;
      h[nt][r] += silu_f(acc[nt][r] + sBias[col]);
      sIn[rl*LDA+col] = (_Float16)h[nt][r];
    }
  // ra1 residual
  do_gemm(ra_w + 32768, ra_b + 256);
  #pragma unroll
  for (int nt=0;nt<8;nt++)
    #pragma unroll
    for (int r=0;r<4;r++){
      int rl=wave*16+q*4+r, col=nt*16+l15;
      sIn[rl*LDA+col] = (_Float16)silu_f(acc[nt][r] + sBias[col]);
    }
  do_gemm(ra_w + 49152, ra_b + 384);
  // final h update, f32 out via LDS roundtrip (sW reused as f32 scratch)
  float* scr = reinterpret_cast<float*>(sW);
  #pragma unroll
  for (int nt=0;nt<8;nt++)
    #pragma unroll
    for (int r=0;r<4;r++){
      int rl=wave*16+q*4+r, col=nt*16+l15;
      h[nt][r] += silu_f(acc[nt][r] + sBias[col]);
      scr[rl*LDF+col] = h[nt][r];
    }
  __syncthreads();
  {
    int row=tid>>2, cs=(tid&3)*32;
    if (e0+row < E)
      #pragma unroll
      for (int i=0;i<8;i++)
        *reinterpret_cast<float4*>(out + (size_t)(e0+row)*H + cs + i*4) =
          *reinterpret_cast<const float4*>(&scr[row*LDF + cs + i*4]);
  }
}

extern "C" void kernel_launch(void* const* d_in, const int* in_sizes, int n_in,
                              void* d_out, int out_size, void* d_ws, size_t ws_size,
                              hipStream_t stream)
{
  const float* x      = (const float*)d_in[0];
  const float* radial = (const float*)d_in[1];
  const float* sph    = (const float*)d_in[2];
  const int* e_from   = (const int*)d_in[3];
  const int* e_to     = (const int*)d_in[4];
  const float* w_rbf  = (const float*)d_in[5];
  const float* w_sbf  = (const float*)d_in[6];
  const float* w_from = (const float*)d_in[7];
  const float* b_from = (const float*)d_in[8];
  const float* w_to   = (const float*)d_in[9];
  const float* b_to   = (const float*)d_in[10];
  const float* Wb     = (const float*)d_in[11];
  const float* rb_w   = (const float*)d_in[12];
  const float* rb_b   = (const float*)d_in[13];
  const float* lin_w  = (const float*)d_in[14];
  const float* lin_b  = (const float*)d_in[15];
  const float* ra_w   = (const float*)d_in[16];
  const float* ra_b   = (const float*)d_in[17];

  int E = in_sizes[0] / H;      // 100000
  int T = in_sizes[3];          // 262144

  float*    agg  = (float*)d_out;      // f32 [E][H], 1:1 with output rows
  _Float16* x_kj = (_Float16*)d_ws;    // f16 [E][H], 25.6 MB, sole ws use

  edge_kernel<<<(E+63)/64, 256, 0, stream>>>(x, radial, w_rbf, w_from, b_from,
                                             w_to, b_to, x_kj, agg, E);
  bilinear_kernel<<<T/128, 256, 0, stream>>>(x_kj, sph, w_sbf, Wb, e_from, e_to, agg);
  post_kernel<<<(E+63)/64, 256, 0, stream>>>(x, agg, rb_w, rb_b, lin_w, lin_b,
                                             ra_w, ra_b, (float*)d_out, E);
}